// Round 1
// baseline (686.254 us; speedup 1.0000x reference)
//
#include <hip/hip_runtime.h>
#include <math.h>

#define D_DIM 512
#define K_DIM 112
#define TOPK 5
#define LAMBDA_ 5.0f

#define BM 128          // rows per block
#define BK 64           // D-chunk
#define TM 8            // rows per thread
#define TN 7            // clusters per thread
#define NTHREADS 256    // 16 row-groups x 16 cluster-groups

struct __align__(16) SMem {
  union {
    struct {
      float xs[BK][BM + 4];      // x tile, transposed [d][r]; +4 keeps 16B align, breaks bank stride
      float cs[BK][K_DIM + 4];   // C tile, transposed [d][k]
    } g;                          // 33792 + 29696 = 63488 B
    struct {
      float sims[BM][K_DIM + 1]; // stride 113 -> conflict-free column scan
      float sc[BM][TOPK];        // lambda * softmax score
      int   si[BM][TOPK];        // top-5 cluster indices
    } p;                          // 57856 + 2560 + 2560 = 62976 B
  } u;
};

__global__ __launch_bounds__(NTHREADS, 2)
void tse_fused(const float* __restrict__ x, const float* __restrict__ cc,
               float* __restrict__ out) {
  __shared__ SMem sm;
  const int tid = threadIdx.x;
  const int tx = tid & 15;   // row group: rows tx*8 .. tx*8+7
  const int ky = tid >> 4;   // cluster group: clusters ky*7 .. ky*7+6
  const long long row0 = (long long)blockIdx.x * BM;

  float acc[TM][TN];
#pragma unroll
  for (int i = 0; i < TM; ++i)
#pragma unroll
    for (int j = 0; j < TN; ++j) acc[i][j] = 0.0f;

  for (int dc = 0; dc < D_DIM; dc += BK) {
    // ---- stage x tile (transposed): BM*BK floats, 8 float4 per thread ----
#pragma unroll
    for (int it = 0; it < (BM * BK / 4) / NTHREADS; ++it) {
      int id = it * NTHREADS + tid;
      int r  = id >> 4;          // 16 float4 per row (BK/4)
      int dg = id & 15;
      float4 v = *(const float4*)(x + (row0 + r) * D_DIM + dc + dg * 4);
      sm.u.g.xs[dg * 4 + 0][r] = v.x;
      sm.u.g.xs[dg * 4 + 1][r] = v.y;
      sm.u.g.xs[dg * 4 + 2][r] = v.z;
      sm.u.g.xs[dg * 4 + 3][r] = v.w;
    }
    // ---- stage C tile (transposed): K*BK floats, 7 float4 per thread ----
#pragma unroll
    for (int it = 0; it < (K_DIM * BK / 4) / NTHREADS; ++it) {
      int id = it * NTHREADS + tid;
      int k  = id >> 4;
      int dg = id & 15;
      float4 v = *(const float4*)(cc + (long long)k * D_DIM + dc + dg * 4);
      sm.u.g.cs[dg * 4 + 0][k] = v.x;
      sm.u.g.cs[dg * 4 + 1][k] = v.y;
      sm.u.g.cs[dg * 4 + 2][k] = v.z;
      sm.u.g.cs[dg * 4 + 3][k] = v.w;
    }
    __syncthreads();

    // ---- register-tiled FMA inner loop: 56 FMA per d-step per thread ----
#pragma unroll 4
    for (int d = 0; d < BK; ++d) {
      float4 xa = *(const float4*)&sm.u.g.xs[d][tx * TM];      // 16B aligned (stride 132)
      float4 xb = *(const float4*)&sm.u.g.xs[d][tx * TM + 4];
      float xf[TM] = {xa.x, xa.y, xa.z, xa.w, xb.x, xb.y, xb.z, xb.w};
      float cf[TN];
#pragma unroll
      for (int j = 0; j < TN; ++j) cf[j] = sm.u.g.cs[d][ky * TN + j];
#pragma unroll
      for (int i = 0; i < TM; ++i)
#pragma unroll
        for (int j = 0; j < TN; ++j)
          acc[i][j] = fmaf(xf[i], cf[j], acc[i][j]);
    }
    __syncthreads();  // protects union re-use (last reads of g before p writes)
  }

  // ---- dump sims to LDS ----
#pragma unroll
  for (int i = 0; i < TM; ++i)
#pragma unroll
    for (int j = 0; j < TN; ++j)
      sm.u.p.sims[tx * TM + i][ky * TN + j] = acc[i][j];
  __syncthreads();

  // ---- per-row top-5 + softmax (threads 0..127, one row each) ----
  if (tid < BM) {
    float tv[TOPK];
    int   ti[TOPK];
#pragma unroll
    for (int i = 0; i < TOPK; ++i) { tv[i] = -3.0e38f; ti[i] = 0; }
    for (int k = 0; k < K_DIM; ++k) {
      float v = sm.u.p.sims[tid][k];
      if (v > tv[TOPK - 1]) {             // strict > : lax.top_k tie rule (lowest index wins)
        tv[TOPK - 1] = v; ti[TOPK - 1] = k;
#pragma unroll
        for (int i = TOPK - 2; i >= 0; --i) {
          if (tv[i + 1] > tv[i]) {
            float tf = tv[i]; tv[i] = tv[i + 1]; tv[i + 1] = tf;
            int   tq = ti[i]; ti[i] = ti[i + 1]; ti[i + 1] = tq;
          }
        }
      }
    }
    float m = tv[0];                       // sorted descending -> max
    float e[TOPK];
    float z = 0.0f;
#pragma unroll
    for (int i = 0; i < TOPK; ++i) { e[i] = __expf(tv[i] - m); z += e[i]; }
    float s = LAMBDA_ / z;
#pragma unroll
    for (int i = 0; i < TOPK; ++i) {
      sm.u.p.sc[tid][i] = e[i] * s;
      sm.u.p.si[tid][i] = ti[i];
    }
  }
  __syncthreads();

  // ---- epilogue: out = x + sum_k sc_k * C[si_k], coalesced float4 sweep ----
  // lanes 0..63 of a wave share r -> sc/si reads broadcast, C gathers wave-uniform+coalesced
  {
    const int dg = tid & 127;       // float4 column within row (D/4 = 128)
    int r = tid >> 7;               // 0 or 1
    for (; r < BM; r += NTHREADS / 128) {
      const long long base = (row0 + r) * D_DIM + dg * 4;
      float4 o = *(const float4*)(x + base);
#pragma unroll
      for (int t = 0; t < TOPK; ++t) {
        float w  = sm.u.p.sc[r][t];
        int   ix = sm.u.p.si[r][t];
        float4 cv = *(const float4*)(cc + (long long)ix * D_DIM + dg * 4);
        o.x = fmaf(w, cv.x, o.x);
        o.y = fmaf(w, cv.y, o.y);
        o.z = fmaf(w, cv.z, o.z);
        o.w = fmaf(w, cv.w, o.w);
      }
      *(float4*)(out + base) = o;
    }
  }
}

extern "C" void kernel_launch(void* const* d_in, const int* in_sizes, int n_in,
                              void* d_out, int out_size, void* d_ws, size_t ws_size,
                              hipStream_t stream) {
  const float* x  = (const float*)d_in[0];
  const float* cc = (const float*)d_in[1];
  float* out = (float*)d_out;
  const int Btot = in_sizes[0] / D_DIM;   // 131072
  const int grid = Btot / BM;             // 1024
  tse_fused<<<dim3(grid), dim3(NTHREADS), 0, stream>>>(x, cc, out);
}